// Round 1
// baseline (1127.167 us; speedup 1.0000x reference)
//
#include <hip/hip_runtime.h>
#include <hip/hip_bf16.h>

// Problem constants
#define BB 4
#define NN 4096
#define DD 2048
#define HH 16
#define DK 128
#define MTOK (BB * NN)       // 16384 tokens
#define QKVW (3 * DD)        // 6144

typedef __bf16 bf16x8 __attribute__((ext_vector_type(8)));
typedef __bf16 bf16x4 __attribute__((ext_vector_type(4)));
typedef float f32x4 __attribute__((ext_vector_type(4)));

// ---- async global -> LDS, 16 bytes per lane (lane lands at ldsbase + lane*16) ----
__device__ __forceinline__ void gload16(const __bf16* g, __bf16* lds_wave_uniform_base) {
    __builtin_amdgcn_global_load_lds(
        (const __attribute__((address_space(1))) void*)g,
        (__attribute__((address_space(3))) void*)lds_wave_uniform_base,
        16, 0, 0);
}

// ------------------------------------------------------------------
// X fp32 -> bf16 elementwise convert (vectorized float4 -> bf16x4)
// ------------------------------------------------------------------
__global__ __launch_bounds__(256) void xconv_kernel(const float* __restrict__ X,
                                                    __bf16* __restrict__ Xb, int n4) {
    int i = blockIdx.x * blockDim.x + threadIdx.x;
    if (i < n4) {
        float4 v = reinterpret_cast<const float4*>(X)[i];
        bf16x4 o;
        o[0] = (__bf16)v.x; o[1] = (__bf16)v.y; o[2] = (__bf16)v.z; o[3] = (__bf16)v.w;
        reinterpret_cast<bf16x4*>(Xb)[i] = o;
    }
}

// ------------------------------------------------------------------
// Weight transpose-convert: W (K=2048, N=2048) fp32 row-major -> Wt (N, K) bf16
// blockIdx.z selects which weight; 0,1,2 -> Wcat slots (q,k,v), 3 -> Wo_t
// ------------------------------------------------------------------
__global__ __launch_bounds__(256) void wconv_kernel(const float* __restrict__ W0,
                                                    const float* __restrict__ W1,
                                                    const float* __restrict__ W2,
                                                    const float* __restrict__ W3,
                                                    __bf16* __restrict__ Wcat,
                                                    __bf16* __restrict__ Wo_t) {
    __shared__ float tile[32][33];
    const int w = blockIdx.z;
    const float* W = (w == 0) ? W0 : (w == 1) ? W1 : (w == 2) ? W2 : W3;
    __bf16* dst = (w < 3) ? (Wcat + (size_t)w * DD * DD) : Wo_t;
    const int tx = threadIdx.x, ty = threadIdx.y;     // block (32, 8)
    const int n0 = blockIdx.x * 32, k0 = blockIdx.y * 32;
#pragma unroll
    for (int j = 0; j < 32; j += 8)
        tile[ty + j][tx] = W[(size_t)(k0 + ty + j) * DD + n0 + tx];
    __syncthreads();
#pragma unroll
    for (int j = 0; j < 32; j += 8)
        dst[(size_t)(n0 + ty + j) * DD + k0 + tx] = (__bf16)tile[tx][ty + j];
}

// ------------------------------------------------------------------
// GEMM: C[M,N] = A[M,K] @ B[K,N], with B supplied transposed (Bt: N x K).
// A row-major bf16 (row stride lda), Bt row-major bf16 (row stride ldb = K),
// C row-major OutT (row stride ldc).
// Block tile 128x128, BK=64, 256 threads = 4 waves in 2x2, each wave 64x64
// via 4x4 grid of 16x16x32 bf16 MFMAs. m97 structure (global_load_lds w=16).
// M, N, K all multiples of 128/64 -> no bounds checks.
// ------------------------------------------------------------------
template <typename OutT>
__global__ __launch_bounds__(256) void gemm_bt(const __bf16* __restrict__ A, int lda,
                                               const __bf16* __restrict__ Bt, int ldb,
                                               OutT* __restrict__ C, int ldc, int K) {
    constexpr int BM = 128, BN = 128, BK = 64;
    __shared__ __align__(16) __bf16 As[BM * BK];
    __shared__ __align__(16) __bf16 Bs[BN * BK];

    const int tid = threadIdx.x;
    const int wave = tid >> 6;
    const int lane = tid & 63;
    const int t = lane & 15;        // MFMA row/col selector
    const int quad = lane >> 4;     // MFMA k-group selector
    const int wm = wave >> 1;       // wave row (0..1)
    const int wn = wave & 1;        // wave col (0..1)
    const size_t blockM = blockIdx.y * BM;
    const size_t blockN = blockIdx.x * BN;

    // staging: lane covers row (groupbase + lane/8), cols (lane%8)*8 .. +8
    const int srow = lane >> 3;
    const int scol = (lane & 7) * 8;

    f32x4 acc[4][4];
#pragma unroll
    for (int mi = 0; mi < 4; ++mi)
#pragma unroll
        for (int ni = 0; ni < 4; ++ni) acc[mi][ni] = (f32x4){0.f, 0.f, 0.f, 0.f};

    for (int k0 = 0; k0 < K; k0 += BK) {
#pragma unroll
        for (int it = 0; it < 4; ++it) {
            const int rbase = it * 32 + wave * 8;          // wave-uniform
            const int r = rbase + srow;
            gload16(A + (blockM + r) * (size_t)lda + k0 + scol, &As[rbase * BK]);
            gload16(Bt + (blockN + r) * (size_t)ldb + k0 + scol, &Bs[rbase * BK]);
        }
        __syncthreads();   // compiler drains vmcnt before s_barrier

#pragma unroll
        for (int kk = 0; kk < 2; ++kk) {
            bf16x8 af[4], bfr[4];
#pragma unroll
            for (int mi = 0; mi < 4; ++mi)
                af[mi] = *reinterpret_cast<const bf16x8*>(
                    As + (wm * 64 + mi * 16 + t) * BK + kk * 32 + quad * 8);
#pragma unroll
            for (int ni = 0; ni < 4; ++ni)
                bfr[ni] = *reinterpret_cast<const bf16x8*>(
                    Bs + (wn * 64 + ni * 16 + t) * BK + kk * 32 + quad * 8);
#pragma unroll
            for (int mi = 0; mi < 4; ++mi)
#pragma unroll
                for (int ni = 0; ni < 4; ++ni)
                    acc[mi][ni] = __builtin_amdgcn_mfma_f32_16x16x32_bf16(
                        af[mi], bfr[ni], acc[mi][ni], 0, 0, 0);
        }
        __syncthreads();
    }

    // epilogue: C/D layout col = lane&15, row = quad*4 + reg  [m89-verified]
#pragma unroll
    for (int mi = 0; mi < 4; ++mi) {
#pragma unroll
        for (int i = 0; i < 4; ++i) {
            const size_t row = blockM + wm * 64 + mi * 16 + quad * 4 + i;
#pragma unroll
            for (int ni = 0; ni < 4; ++ni) {
                const size_t col = blockN + wn * 64 + ni * 16 + t;
                C[row * (size_t)ldc + col] = (OutT)acc[mi][ni][i];
            }
        }
    }
}

// ------------------------------------------------------------------
// Per-token attention. QKV rows: [q(2048) | k(2048) | v(2048)], bf16.
// One wave per token. scores = q @ k^T via 4 MFMAs (16x16x128), scores->LDS,
// o = scores @ v on VALU (fp32 acc), O written bf16 IN PLACE over the q region.
// ------------------------------------------------------------------
__global__ __launch_bounds__(256) void attn_kernel(__bf16* __restrict__ qkv) {
    __shared__ float sc[4][16][17];   // +1 pad: o-stage reads stride 17 -> no 4-way conflict
    const int tid = threadIdx.x;
    const int wave = tid >> 6;
    const int lane = tid & 63;
    const int t = lane & 15;
    const int quad = lane >> 4;
    const size_t token = (size_t)blockIdx.x * 4 + wave;
    __bf16* row = qkv + token * QKVW;

    // scores: A = q (M=16 heads x K=128), B-frag = k[n=t][k-dim] (contiguous)
    f32x4 s = (f32x4){0.f, 0.f, 0.f, 0.f};
#pragma unroll
    for (int ks = 0; ks < 4; ++ks) {
        bf16x8 a = *reinterpret_cast<const bf16x8*>(row + t * DK + ks * 32 + quad * 8);
        bf16x8 b = *reinterpret_cast<const bf16x8*>(row + DD + t * DK + ks * 32 + quad * 8);
        s = __builtin_amdgcn_mfma_f32_16x16x32_bf16(a, b, s, 0, 0, 0);
    }
#pragma unroll
    for (int i = 0; i < 4; ++i) sc[wave][quad * 4 + i][t] = s[i];  // s[h=quad*4+i][j=t]
    __syncthreads();

    // o[h][d] = sum_j s[h][j] * v[j][d]; lane covers heads {quad,quad+4,quad+8,quad+12},
    // d = t*8 .. t*8+7
    const int d0 = t * 8;
    float oa[4][8];
#pragma unroll
    for (int i = 0; i < 4; ++i)
#pragma unroll
        for (int e = 0; e < 8; ++e) oa[i][e] = 0.f;

#pragma unroll
    for (int j = 0; j < 16; ++j) {
        bf16x8 v8 = *reinterpret_cast<const bf16x8*>(row + 2 * DD + j * DK + d0);
        float vf[8];
#pragma unroll
        for (int e = 0; e < 8; ++e) vf[e] = (float)v8[e];
#pragma unroll
        for (int i = 0; i < 4; ++i) {
            const float sj = sc[wave][quad + 4 * i][j];
#pragma unroll
            for (int e = 0; e < 8; ++e) oa[i][e] += sj * vf[e];
        }
    }
#pragma unroll
    for (int i = 0; i < 4; ++i) {
        bf16x8 o8;
#pragma unroll
        for (int e = 0; e < 8; ++e) o8[e] = (__bf16)oa[i][e];
        *reinterpret_cast<bf16x8*>(row + (quad + 4 * i) * DK + d0) = o8;  // O over q region
    }
}

// ------------------------------------------------------------------
extern "C" void kernel_launch(void* const* d_in, const int* in_sizes, int n_in,
                              void* d_out, int out_size, void* d_ws, size_t ws_size,
                              hipStream_t stream) {
    const float* X  = (const float*)d_in[0];
    const float* Wq = (const float*)d_in[1];
    const float* Wk = (const float*)d_in[2];
    const float* Wv = (const float*)d_in[3];
    const float* Wo = (const float*)d_in[4];
    float* out = (float*)d_out;

    // workspace layout (bf16): [Wcat_t 3*D*D][Wo_t D*D][Xb M*D][QKV M*3D] = 302 MB
    char* ws = (char*)d_ws;
    __bf16* Wcat = (__bf16*)ws;
    __bf16* Wo_t = (__bf16*)(ws + (size_t)3 * DD * DD * 2);
    __bf16* Xb   = (__bf16*)(ws + (size_t)4 * DD * DD * 2);
    __bf16* QKV  = (__bf16*)(ws + (size_t)4 * DD * DD * 2 + (size_t)MTOK * DD * 2);

    // 1) X -> bf16
    const int n4 = MTOK * DD / 4;
    xconv_kernel<<<(n4 + 255) / 256, 256, 0, stream>>>(X, Xb, n4);

    // 2) weights -> bf16, transposed to (N, K)
    wconv_kernel<<<dim3(DD / 32, DD / 32, 4), dim3(32, 8), 0, stream>>>(
        Wq, Wk, Wv, Wo, Wcat, Wo_t);

    // 3) QKV = Xb @ [Wq|Wk|Wv]  (M=16384, N=6144, K=2048), bf16 out
    gemm_bt<__bf16><<<dim3(QKVW / 128, MTOK / 128), 256, 0, stream>>>(
        Xb, DD, Wcat, DD, QKV, QKVW, DD);

    // 4) per-token attention, O overwrites the q slice of QKV
    attn_kernel<<<MTOK / 4, 256, 0, stream>>>(QKV);

    // 5) out = O @ Wo  (A = QKV with lda=6144, O in cols 0..2047), fp32 out
    gemm_bt<float><<<dim3(DD / 128, MTOK / 128), 256, 0, stream>>>(
        QKV, QKVW, Wo_t, DD, out, DD, DD);
}

// Round 2
// 910.030 us; speedup vs baseline: 1.2386x; 1.2386x over previous
//
#include <hip/hip_runtime.h>
#include <hip/hip_bf16.h>

// Problem constants
#define BB 4
#define NN 4096
#define DD 2048
#define HH 16
#define DK 128
#define MTOK (BB * NN)       // 16384 tokens
#define QKVW (3 * DD)        // 6144

typedef __bf16 bf16x8 __attribute__((ext_vector_type(8)));
typedef __bf16 bf16x4 __attribute__((ext_vector_type(4)));
typedef float f32x4 __attribute__((ext_vector_type(4)));

// ---- async global -> LDS, 16 bytes per lane (lane lands at ldsbase + lane*16) ----
__device__ __forceinline__ void gload16(const __bf16* g, __bf16* lds_wave_uniform_base) {
    __builtin_amdgcn_global_load_lds(
        (const __attribute__((address_space(1))) void*)g,
        (__attribute__((address_space(3))) void*)lds_wave_uniform_base,
        16, 0, 0);
}

// ------------------------------------------------------------------
// X fp32 -> bf16 elementwise convert (vectorized float4 -> bf16x4)
// ------------------------------------------------------------------
__global__ __launch_bounds__(256) void xconv_kernel(const float* __restrict__ X,
                                                    __bf16* __restrict__ Xb, int n4) {
    int i = blockIdx.x * blockDim.x + threadIdx.x;
    if (i < n4) {
        float4 v = reinterpret_cast<const float4*>(X)[i];
        bf16x4 o;
        o[0] = (__bf16)v.x; o[1] = (__bf16)v.y; o[2] = (__bf16)v.z; o[3] = (__bf16)v.w;
        reinterpret_cast<bf16x4*>(Xb)[i] = o;
    }
}

// ------------------------------------------------------------------
// Weight transpose-convert: W (K=2048, N=2048) fp32 row-major -> Wt (N, K) bf16
// blockIdx.z selects which weight; 0,1,2 -> Wcat slots (q,k,v), 3 -> Wo_t
// ------------------------------------------------------------------
__global__ __launch_bounds__(256) void wconv_kernel(const float* __restrict__ W0,
                                                    const float* __restrict__ W1,
                                                    const float* __restrict__ W2,
                                                    const float* __restrict__ W3,
                                                    __bf16* __restrict__ Wcat,
                                                    __bf16* __restrict__ Wo_t) {
    __shared__ float tile[32][33];
    const int w = blockIdx.z;
    const float* W = (w == 0) ? W0 : (w == 1) ? W1 : (w == 2) ? W2 : W3;
    __bf16* dst = (w < 3) ? (Wcat + (size_t)w * DD * DD) : Wo_t;
    const int tx = threadIdx.x, ty = threadIdx.y;     // block (32, 8)
    const int n0 = blockIdx.x * 32, k0 = blockIdx.y * 32;
#pragma unroll
    for (int j = 0; j < 32; j += 8)
        tile[ty + j][tx] = W[(size_t)(k0 + ty + j) * DD + n0 + tx];
    __syncthreads();
#pragma unroll
    for (int j = 0; j < 32; j += 8)
        dst[(size_t)(n0 + ty + j) * DD + k0 + tx] = (__bf16)tile[tx][ty + j];
}

// ------------------------------------------------------------------
// GEMM: C[M,N] = A[M,K] @ B[K,N], with B supplied transposed (Bt: N x K).
// Block tile 128x128, BK=64, 256 threads = 4 waves in 2x2, each wave 64x64
// via 4x4 grid of 16x16x32 bf16 MFMAs. m97 structure (global_load_lds w=16).
//
// LDS layout is XOR-swizzled to kill ds_read_b128 bank conflicts:
//   16-B chunk c (c=0..7) of row r is stored at slot (c ^ (r&7)).
//   Write side: lane l (forced LDS dst = base + l*16) fetches global chunk
//   ((l&7) ^ (l>>3)) of row (l>>3) -- permutation within one 128-B segment,
//   coalescing unchanged.
//   Read side: slot = (kk*4+quad) ^ (t&7) -> all 8 bank-groups hit by exactly
//   8 lanes each = conflict-free minimum (was: 16 lanes on 4 groups = 2x).
// ------------------------------------------------------------------
template <typename OutT>
__global__ __launch_bounds__(256) void gemm_bt(const __bf16* __restrict__ A, int lda,
                                               const __bf16* __restrict__ Bt, int ldb,
                                               OutT* __restrict__ C, int ldc, int K) {
    constexpr int BM = 128, BN = 128, BK = 64;
    __shared__ __align__(16) __bf16 As[BM * BK];
    __shared__ __align__(16) __bf16 Bs[BN * BK];

    const int tid = threadIdx.x;
    const int wave = tid >> 6;
    const int lane = tid & 63;
    const int t = lane & 15;        // MFMA row/col selector
    const int quad = lane >> 4;     // MFMA k-group selector
    const int wm = wave >> 1;       // wave row (0..1)
    const int wn = wave & 1;        // wave col (0..1)
    const size_t blockM = blockIdx.y * BM;
    const size_t blockN = blockIdx.x * BN;

    // staging: lane l covers row (rbase + l/8), swizzled chunk ((l&7)^(l>>3))
    const int srow = lane >> 3;
    const int scol = ((lane & 7) ^ srow) * 8;   // XOR-swizzled source chunk

    f32x4 acc[4][4];
#pragma unroll
    for (int mi = 0; mi < 4; ++mi)
#pragma unroll
        for (int ni = 0; ni < 4; ++ni) acc[mi][ni] = (f32x4){0.f, 0.f, 0.f, 0.f};

    for (int k0 = 0; k0 < K; k0 += BK) {
#pragma unroll
        for (int it = 0; it < 4; ++it) {
            const int rbase = it * 32 + wave * 8;          // wave-uniform, %8 == 0
            const int r = rbase + srow;
            gload16(A + (blockM + r) * (size_t)lda + k0 + scol, &As[rbase * BK]);
            gload16(Bt + (blockN + r) * (size_t)ldb + k0 + scol, &Bs[rbase * BK]);
        }
        __syncthreads();   // compiler drains vmcnt before s_barrier

#pragma unroll
        for (int kk = 0; kk < 2; ++kk) {
            bf16x8 af[4], bfr[4];
#pragma unroll
            for (int mi = 0; mi < 4; ++mi)
                af[mi] = *reinterpret_cast<const bf16x8*>(
                    As + (wm * 64 + mi * 16 + t) * BK + (((kk * 4 + quad) ^ (t & 7)) * 8));
#pragma unroll
            for (int ni = 0; ni < 4; ++ni)
                bfr[ni] = *reinterpret_cast<const bf16x8*>(
                    Bs + (wn * 64 + ni * 16 + t) * BK + (((kk * 4 + quad) ^ (t & 7)) * 8));
#pragma unroll
            for (int mi = 0; mi < 4; ++mi)
#pragma unroll
                for (int ni = 0; ni < 4; ++ni)
                    acc[mi][ni] = __builtin_amdgcn_mfma_f32_16x16x32_bf16(
                        af[mi], bfr[ni], acc[mi][ni], 0, 0, 0);
        }
        __syncthreads();
    }

    // epilogue: C/D layout col = lane&15, row = quad*4 + reg  [m89-verified]
#pragma unroll
    for (int mi = 0; mi < 4; ++mi) {
#pragma unroll
        for (int i = 0; i < 4; ++i) {
            const size_t row = blockM + wm * 64 + mi * 16 + quad * 4 + i;
#pragma unroll
            for (int ni = 0; ni < 4; ++ni) {
                const size_t col = blockN + wn * 64 + ni * 16 + t;
                C[row * (size_t)ldc + col] = (OutT)acc[mi][ni][i];
            }
        }
    }
}

// ------------------------------------------------------------------
// Per-token attention. QKV rows: [q(2048) | k(2048) | v(2048)], bf16.
// One wave per token. scores = q @ k^T via 4 MFMAs (16x16x128), scores->LDS,
// o = scores @ v on VALU (fp32 acc), O written bf16 IN PLACE over the q region.
// ------------------------------------------------------------------
__global__ __launch_bounds__(256) void attn_kernel(__bf16* __restrict__ qkv) {
    __shared__ float sc[4][16][17];   // +1 pad
    const int tid = threadIdx.x;
    const int wave = tid >> 6;
    const int lane = tid & 63;
    const int t = lane & 15;
    const int quad = lane >> 4;
    const size_t token = (size_t)blockIdx.x * 4 + wave;
    __bf16* row = qkv + token * QKVW;

    // scores: A = q (M=16 heads x K=128), B-frag = k[n=t][k-dim] (contiguous)
    f32x4 s = (f32x4){0.f, 0.f, 0.f, 0.f};
#pragma unroll
    for (int ks = 0; ks < 4; ++ks) {
        bf16x8 a = *reinterpret_cast<const bf16x8*>(row + t * DK + ks * 32 + quad * 8);
        bf16x8 b = *reinterpret_cast<const bf16x8*>(row + DD + t * DK + ks * 32 + quad * 8);
        s = __builtin_amdgcn_mfma_f32_16x16x32_bf16(a, b, s, 0, 0, 0);
    }
#pragma unroll
    for (int i = 0; i < 4; ++i) sc[wave][quad * 4 + i][t] = s[i];  // s[h=quad*4+i][j=t]
    __syncthreads();

    // o[h][d] = sum_j s[h][j] * v[j][d]; lane covers heads {quad,quad+4,quad+8,quad+12},
    // d = t*8 .. t*8+7
    const int d0 = t * 8;
    float oa[4][8];
#pragma unroll
    for (int i = 0; i < 4; ++i)
#pragma unroll
        for (int e = 0; e < 8; ++e) oa[i][e] = 0.f;

#pragma unroll
    for (int j = 0; j < 16; ++j) {
        bf16x8 v8 = *reinterpret_cast<const bf16x8*>(row + 2 * DD + j * DK + d0);
        float vf[8];
#pragma unroll
        for (int e = 0; e < 8; ++e) vf[e] = (float)v8[e];
#pragma unroll
        for (int i = 0; i < 4; ++i) {
            const float sj = sc[wave][quad + 4 * i][j];
#pragma unroll
            for (int e = 0; e < 8; ++e) oa[i][e] += sj * vf[e];
        }
    }
#pragma unroll
    for (int i = 0; i < 4; ++i) {
        bf16x8 o8;
#pragma unroll
        for (int e = 0; e < 8; ++e) o8[e] = (__bf16)oa[i][e];
        *reinterpret_cast<bf16x8*>(row + (quad + 4 * i) * DK + d0) = o8;  // O over q region
    }
}

// ------------------------------------------------------------------
extern "C" void kernel_launch(void* const* d_in, const int* in_sizes, int n_in,
                              void* d_out, int out_size, void* d_ws, size_t ws_size,
                              hipStream_t stream) {
    const float* X  = (const float*)d_in[0];
    const float* Wq = (const float*)d_in[1];
    const float* Wk = (const float*)d_in[2];
    const float* Wv = (const float*)d_in[3];
    const float* Wo = (const float*)d_in[4];
    float* out = (float*)d_out;

    // workspace layout (bf16): [Wcat_t 3*D*D][Wo_t D*D][Xb M*D][QKV M*3D] = 302 MB
    char* ws = (char*)d_ws;
    __bf16* Wcat = (__bf16*)ws;
    __bf16* Wo_t = (__bf16*)(ws + (size_t)3 * DD * DD * 2);
    __bf16* Xb   = (__bf16*)(ws + (size_t)4 * DD * DD * 2);
    __bf16* QKV  = (__bf16*)(ws + (size_t)4 * DD * DD * 2 + (size_t)MTOK * DD * 2);

    // 1) X -> bf16
    const int n4 = MTOK * DD / 4;
    xconv_kernel<<<(n4 + 255) / 256, 256, 0, stream>>>(X, Xb, n4);

    // 2) weights -> bf16, transposed to (N, K)
    wconv_kernel<<<dim3(DD / 32, DD / 32, 4), dim3(32, 8), 0, stream>>>(
        Wq, Wk, Wv, Wo, Wcat, Wo_t);

    // 3) QKV = Xb @ [Wq|Wk|Wv]  (M=16384, N=6144, K=2048), bf16 out
    gemm_bt<__bf16><<<dim3(QKVW / 128, MTOK / 128), 256, 0, stream>>>(
        Xb, DD, Wcat, DD, QKV, QKVW, DD);

    // 4) per-token attention, O overwrites the q slice of QKV
    attn_kernel<<<MTOK / 4, 256, 0, stream>>>(QKV);

    // 5) out = O @ Wo  (A = QKV with lda=6144, O in cols 0..2047), fp32 out
    gemm_bt<float><<<dim3(DD / 128, MTOK / 128), 256, 0, stream>>>(
        QKV, QKVW, Wo_t, DD, out, DD, DD);
}

// Round 3
// 908.941 us; speedup vs baseline: 1.2401x; 1.0012x over previous
//
#include <hip/hip_runtime.h>
#include <hip/hip_bf16.h>

// Problem constants
#define BB 4
#define NN 4096
#define DD 2048
#define HH 16
#define DK 128
#define MTOK (BB * NN)       // 16384 tokens
#define QKVW (3 * DD)        // 6144

typedef __bf16 bf16x8 __attribute__((ext_vector_type(8)));
typedef __bf16 bf16x4 __attribute__((ext_vector_type(4)));
typedef float f32x4 __attribute__((ext_vector_type(4)));
typedef float f32x16 __attribute__((ext_vector_type(16)));

// ---- async global -> LDS, 16 bytes per lane (lane lands at ldsbase + lane*16) ----
__device__ __forceinline__ void gload16(const __bf16* g, __bf16* lds_wave_uniform_base) {
    __builtin_amdgcn_global_load_lds(
        (const __attribute__((address_space(1))) void*)g,
        (__attribute__((address_space(3))) void*)lds_wave_uniform_base,
        16, 0, 0);
}

// ------------------------------------------------------------------
// X fp32 -> bf16 elementwise convert (vectorized float4 -> bf16x4)
// ------------------------------------------------------------------
__global__ __launch_bounds__(256) void xconv_kernel(const float* __restrict__ X,
                                                    __bf16* __restrict__ Xb, int n4) {
    int i = blockIdx.x * blockDim.x + threadIdx.x;
    if (i < n4) {
        float4 v = reinterpret_cast<const float4*>(X)[i];
        bf16x4 o;
        o[0] = (__bf16)v.x; o[1] = (__bf16)v.y; o[2] = (__bf16)v.z; o[3] = (__bf16)v.w;
        reinterpret_cast<bf16x4*>(Xb)[i] = o;
    }
}

// ------------------------------------------------------------------
// Weight transpose-convert: W (K=2048, N=2048) fp32 row-major -> Wt (N, K) bf16
// ------------------------------------------------------------------
__global__ __launch_bounds__(256) void wconv_kernel(const float* __restrict__ W0,
                                                    const float* __restrict__ W1,
                                                    const float* __restrict__ W2,
                                                    const float* __restrict__ W3,
                                                    __bf16* __restrict__ Wcat,
                                                    __bf16* __restrict__ Wo_t) {
    __shared__ float tile[32][33];
    const int w = blockIdx.z;
    const float* W = (w == 0) ? W0 : (w == 1) ? W1 : (w == 2) ? W2 : W3;
    __bf16* dst = (w < 3) ? (Wcat + (size_t)w * DD * DD) : Wo_t;
    const int tx = threadIdx.x, ty = threadIdx.y;     // block (32, 8)
    const int n0 = blockIdx.x * 32, k0 = blockIdx.y * 32;
#pragma unroll
    for (int j = 0; j < 32; j += 8)
        tile[ty + j][tx] = W[(size_t)(k0 + ty + j) * DD + n0 + tx];
    __syncthreads();
#pragma unroll
    for (int j = 0; j < 32; j += 8)
        dst[(size_t)(n0 + ty + j) * DD + k0 + tx] = (__bf16)tile[tx][ty + j];
}

// ------------------------------------------------------------------
// GEMM: C[M,N] = A[M,K] @ Bt[N,K]^T. Block tile 128x128, BK=64, 4 waves 2x2,
// each wave 64x64 via a 2x2 grid of 32x32x16 bf16 MFMAs (better FLOP/cyc than
// 16x16x32: 8.07 cyc for 32k FLOP vs 4.85 for 16k -- m119). LDS ingest bytes
// unchanged; MFMA pipe demand per block-iter drops 620 -> 516 cyc.
//
// XOR-swizzled LDS (conflict-free, verified 0 conflicts in r2):
//   chunk c of row r stored at slot (c ^ (r&7)); write side fetches global
//   chunk ((l&7)^(l>>3)); read side uses slot ((ks*2+half) ^ (m32&7)).
//
// 32x32x16 fragment layout: A[m][k]: m=lane&31, k=(lane>>5)*8+j (8 bf16/lane);
// B[k][n]: n=lane&31, k=(lane>>5)*8+j (Bs holds Bt[n][k] rows -> same pattern).
// C/D: col=lane&31, row=(reg&3)+8*(reg>>2)+4*(lane>>5)  [m74/m101 verified].
// ------------------------------------------------------------------
template <typename OutT>
__global__ __launch_bounds__(256) void gemm_bt(const __bf16* __restrict__ A, int lda,
                                               const __bf16* __restrict__ Bt, int ldb,
                                               OutT* __restrict__ C, int ldc, int K) {
    constexpr int BM = 128, BN = 128, BK = 64;
    __shared__ __align__(16) __bf16 As[BM * BK];
    __shared__ __align__(16) __bf16 Bs[BN * BK];

    const int tid = threadIdx.x;
    const int wave = tid >> 6;
    const int lane = tid & 63;
    const int m32 = lane & 31;      // MFMA row/col selector (32-wide)
    const int half = lane >> 5;     // MFMA k-half selector
    const int wm = wave >> 1;       // wave row (0..1)
    const int wn = wave & 1;        // wave col (0..1)
    const size_t blockM = blockIdx.y * BM;
    const size_t blockN = blockIdx.x * BN;

    // staging: lane l covers row (rbase + l/8), swizzled chunk ((l&7)^(l>>3))
    const int srow = lane >> 3;
    const int scol = ((lane & 7) ^ srow) * 8;   // XOR-swizzled source chunk

    f32x16 acc[2][2] = {};

    for (int k0 = 0; k0 < K; k0 += BK) {
#pragma unroll
        for (int it = 0; it < 4; ++it) {
            const int rbase = it * 32 + wave * 8;          // wave-uniform, %8 == 0
            const int r = rbase + srow;
            gload16(A + (blockM + r) * (size_t)lda + k0 + scol, &As[rbase * BK]);
            gload16(Bt + (blockN + r) * (size_t)ldb + k0 + scol, &Bs[rbase * BK]);
        }
        __syncthreads();   // compiler drains vmcnt before s_barrier

#pragma unroll
        for (int ks = 0; ks < 4; ++ks) {
            const int chunk = ((ks * 2 + half) ^ (m32 & 7)) * 8;
            bf16x8 af[2], bfr[2];
#pragma unroll
            for (int mi = 0; mi < 2; ++mi)
                af[mi] = *reinterpret_cast<const bf16x8*>(
                    As + (wm * 64 + mi * 32 + m32) * BK + chunk);
#pragma unroll
            for (int ni = 0; ni < 2; ++ni)
                bfr[ni] = *reinterpret_cast<const bf16x8*>(
                    Bs + (wn * 64 + ni * 32 + m32) * BK + chunk);
#pragma unroll
            for (int mi = 0; mi < 2; ++mi)
#pragma unroll
                for (int ni = 0; ni < 2; ++ni)
                    acc[mi][ni] = __builtin_amdgcn_mfma_f32_32x32x16_bf16(
                        af[mi], bfr[ni], acc[mi][ni], 0, 0, 0);
        }
        __syncthreads();
    }

    // epilogue: C/D col = lane&31, row = (reg&3) + 8*(reg>>2) + 4*half
#pragma unroll
    for (int mi = 0; mi < 2; ++mi) {
#pragma unroll
        for (int ni = 0; ni < 2; ++ni) {
            const size_t col = blockN + wn * 64 + ni * 32 + m32;
#pragma unroll
            for (int reg = 0; reg < 16; ++reg) {
                const size_t row = blockM + wm * 64 + mi * 32 +
                                   (reg & 3) + 8 * (reg >> 2) + 4 * half;
                C[row * (size_t)ldc + col] = (OutT)acc[mi][ni][reg];
            }
        }
    }
}

// ------------------------------------------------------------------
// Per-token attention. QKV rows: [q(2048) | k(2048) | v(2048)], bf16.
// One wave per token. scores = q @ k^T via 4 MFMAs (16x16x128), scores->LDS,
// o = scores @ v on VALU (fp32 acc). O written bf16 to COMPACT buffer Ob
// (lda = 2048) for the output GEMM's A-side locality.
// ------------------------------------------------------------------
__global__ __launch_bounds__(256) void attn_kernel(const __bf16* __restrict__ qkv,
                                                   __bf16* __restrict__ Ob) {
    __shared__ float sc[4][16][17];   // +1 pad
    const int tid = threadIdx.x;
    const int wave = tid >> 6;
    const int lane = tid & 63;
    const int t = lane & 15;
    const int quad = lane >> 4;
    const size_t token = (size_t)blockIdx.x * 4 + wave;
    const __bf16* row = qkv + token * QKVW;
    __bf16* orow = Ob + token * DD;

    // scores: A = q (M=16 heads x K=128), B-frag = k[n=t][k-dim] (contiguous)
    f32x4 s = (f32x4){0.f, 0.f, 0.f, 0.f};
#pragma unroll
    for (int ks = 0; ks < 4; ++ks) {
        bf16x8 a = *reinterpret_cast<const bf16x8*>(row + t * DK + ks * 32 + quad * 8);
        bf16x8 b = *reinterpret_cast<const bf16x8*>(row + DD + t * DK + ks * 32 + quad * 8);
        s = __builtin_amdgcn_mfma_f32_16x16x32_bf16(a, b, s, 0, 0, 0);
    }
#pragma unroll
    for (int i = 0; i < 4; ++i) sc[wave][quad * 4 + i][t] = s[i];  // s[h=quad*4+i][j=t]
    __syncthreads();

    // o[h][d] = sum_j s[h][j] * v[j][d]; lane covers heads {quad,quad+4,quad+8,quad+12},
    // d = t*8 .. t*8+7
    const int d0 = t * 8;
    float oa[4][8];
#pragma unroll
    for (int i = 0; i < 4; ++i)
#pragma unroll
        for (int e = 0; e < 8; ++e) oa[i][e] = 0.f;

#pragma unroll
    for (int j = 0; j < 16; ++j) {
        bf16x8 v8 = *reinterpret_cast<const bf16x8*>(row + 2 * DD + j * DK + d0);
        float vf[8];
#pragma unroll
        for (int e = 0; e < 8; ++e) vf[e] = (float)v8[e];
#pragma unroll
        for (int i = 0; i < 4; ++i) {
            const float sj = sc[wave][quad + 4 * i][j];
#pragma unroll
            for (int e = 0; e < 8; ++e) oa[i][e] += sj * vf[e];
        }
    }
#pragma unroll
    for (int i = 0; i < 4; ++i) {
        bf16x8 o8;
#pragma unroll
        for (int e = 0; e < 8; ++e) o8[e] = (__bf16)oa[i][e];
        *reinterpret_cast<bf16x8*>(orow + (quad + 4 * i) * DK + d0) = o8;
    }
}

// ------------------------------------------------------------------
extern "C" void kernel_launch(void* const* d_in, const int* in_sizes, int n_in,
                              void* d_out, int out_size, void* d_ws, size_t ws_size,
                              hipStream_t stream) {
    const float* X  = (const float*)d_in[0];
    const float* Wq = (const float*)d_in[1];
    const float* Wk = (const float*)d_in[2];
    const float* Wv = (const float*)d_in[3];
    const float* Wo = (const float*)d_in[4];
    float* out = (float*)d_out;

    // workspace layout (bf16): [Wcat_t 3*D*D][Wo_t D*D][Xb M*D][QKV M*3D] = 302 MB
    // Xb doubles as the attention-output buffer Ob (Xb dead after QKV GEMM).
    char* ws = (char*)d_ws;
    __bf16* Wcat = (__bf16*)ws;
    __bf16* Wo_t = (__bf16*)(ws + (size_t)3 * DD * DD * 2);
    __bf16* Xb   = (__bf16*)(ws + (size_t)4 * DD * DD * 2);
    __bf16* QKV  = (__bf16*)(ws + (size_t)4 * DD * DD * 2 + (size_t)MTOK * DD * 2);
    __bf16* Ob   = Xb;

    // 1) X -> bf16
    const int n4 = MTOK * DD / 4;
    xconv_kernel<<<(n4 + 255) / 256, 256, 0, stream>>>(X, Xb, n4);

    // 2) weights -> bf16, transposed to (N, K)
    wconv_kernel<<<dim3(DD / 32, DD / 32, 4), dim3(32, 8), 0, stream>>>(
        Wq, Wk, Wv, Wo, Wcat, Wo_t);

    // 3) QKV = Xb @ [Wq|Wk|Wv]  (M=16384, N=6144, K=2048), bf16 out
    gemm_bt<__bf16><<<dim3(QKVW / 128, MTOK / 128), 256, 0, stream>>>(
        Xb, DD, Wcat, DD, QKV, QKVW, DD);

    // 4) per-token attention -> compact Ob (overwrites Xb region)
    attn_kernel<<<MTOK / 4, 256, 0, stream>>>(QKV, Ob);

    // 5) out = Ob @ Wo  (M=16384, N=2048, K=2048), fp32 out
    gemm_bt<float><<<dim3(DD / 128, MTOK / 128), 256, 0, stream>>>(
        Ob, DD, Wo_t, DD, out, DD, DD);
}